// Round 23
// baseline (47.280 us; speedup 1.0000x reference)
//
#include <hip/hip_runtime.h>
#include <hip/hip_bf16.h>
#include <math.h>

// ws layout (floats): [0,917504) fp[64][28][512] conv partials.

typedef _Float16 h4 __attribute__((ext_vector_type(4)));
typedef _Float16 h8 __attribute__((ext_vector_type(8)));
typedef float f32x4 __attribute__((ext_vector_type(4)));

__device__ __forceinline__ h8 cvt8(float4 a, float4 b){
    h8 r; r[0]=(_Float16)a.x; r[1]=(_Float16)a.y; r[2]=(_Float16)a.z; r[3]=(_Float16)a.w;
    r[4]=(_Float16)b.x; r[5]=(_Float16)b.y; r[6]=(_Float16)b.z; r[7]=(_Float16)b.w; return r;
}

// ---------------- conv + relu + partial global-avg-pool via MFMA ----------------
// Grid 64*28, 512 thr, 112 positions (2 output rows). LDS 16KB. (R19 shape —
// proven best across R20/R21/R22 restructure attempts.) Af2/Bf2 both masked to
// kg<2, so the k=48..63 LDS pad region is dead: zero-pad loop removed.
__global__ __launch_bounds__(512) void k_conv_mfma(const float* __restrict__ x,
            const float* __restrict__ Wc, const float* __restrict__ bc,
            float* __restrict__ fp){
    extern __shared__ _Float16 Al[];   // [112][72]
    const int tid = threadIdx.x;
    const int b = blockIdx.x / 28, seg = blockIdx.x % 28;
    for (int idx = tid; idx < 1344; idx += 512){
        int cr = idx / 112, p = idx - cr*112;
        int cc = cr >> 2, r = cr & 3;
        int ro = p / 56, ow = p - ro*56;
        int ih = (seg*2 + ro)*4 + r;
        float4 v = *(const float4*)&x[(((size_t)b*3 + cc)*224 + ih)*224 + ow*4];
        h4 hv; hv[0]=(_Float16)v.x; hv[1]=(_Float16)v.y; hv[2]=(_Float16)v.z; hv[3]=(_Float16)v.w;
        *(h4*)&Al[p*72 + cr*4] = hv;
    }
    const int wv = tid >> 6, lane = tid & 63;
    const int col = lane & 15, kg = lane >> 4;
    const int n0 = wv * 64;
    const h8 hz = {0,0,0,0,0,0,0,0};
    h8 Bf[4], Bf2[4];
    float bias[4], pool[4];
    #pragma unroll
    for (int nt=0; nt<4; ++nt){
        int ch = n0 + nt*16 + col;
        const float* wr = &Wc[ch*48];
        float4 wa = *(const float4*)&wr[kg*8];
        float4 wb = *(const float4*)&wr[kg*8 + 4];
        Bf[nt] = cvt8(wa, wb);
        if (kg < 2){
            float4 wc4 = *(const float4*)&wr[32 + kg*8];
            float4 wd  = *(const float4*)&wr[36 + kg*8];
            Bf2[nt] = cvt8(wc4, wd);
        } else Bf2[nt] = hz;
        bias[nt] = bc[ch];
        pool[nt] = 0.f;
    }
    __syncthreads();
    #pragma unroll
    for (int mt=0; mt<7; ++mt){
        const _Float16* ar = &Al[(mt*16 + col)*72];
        h8 Af  = *(const h8*)&ar[kg*8];
        h8 Af2 = (kg < 2) ? *(const h8*)&ar[32 + kg*8] : hz;
        #pragma unroll
        for (int nt=0; nt<4; ++nt){
            f32x4 acc = {0.f,0.f,0.f,0.f};
            acc = __builtin_amdgcn_mfma_f32_16x16x32_f16(Af,  Bf[nt],  acc, 0,0,0);
            acc = __builtin_amdgcn_mfma_f32_16x16x32_f16(Af2, Bf2[nt], acc, 0,0,0);
            #pragma unroll
            for (int j=0;j<4;++j) pool[nt] += fmaxf(acc[j] + bias[nt], 0.f);
        }
    }
    #pragma unroll
    for (int nt=0; nt<4; ++nt){
        pool[nt] += __shfl_xor(pool[nt], 16);
        pool[nt] += __shfl_xor(pool[nt], 32);
    }
    if (lane < 16){
        float* dst = &fp[((b*28 + seg)<<9) + n0 + lane];
        #pragma unroll
        for (int nt=0; nt<4; ++nt) dst[nt*16] = pool[nt];
    }
}

// ---------------- light-cone VQC: 6-qubit statevector ----------------
// M = U^dag Z0 U supported on wires 0..5 (ascending CNOT chain: backward light
// cone grows 1 wire/layer). 512 thr: feat stage (8-wave TLP) -> 6-wave reduce ->
// wave 0 runs the 64-amp circuit via shfl_xor.
__global__ __launch_bounds__(512) void k_vqc6(
        const float* __restrict__ wgt,   // [6][16][2]
        const float* __restrict__ fp,    // [64][28][512]
        const float* __restrict__ Wr, const float* __restrict__ br,
        float* __restrict__ out){
    __shared__ float featL[512];
    __shared__ float gates[36][4];
    __shared__ float enc[6][2];
    __shared__ float angS[6];
    const int T = threadIdx.x;
    const int b = blockIdx.x;

    {
        float s = 0.f;
        #pragma unroll 4
        for (int seg=0; seg<28; ++seg) s += fp[((b*28 + seg)<<9) + T];
        featL[T] = s;
    }
    __syncthreads();
    {
        int w = T >> 6, l = T & 63;
        if (w < 6){
            float acc = 0.f;
            #pragma unroll
            for (int k=0;k<8;++k)
                acc += (featL[l + 64*k] * (1.0f/3136.0f)) * Wr[w*512 + l + 64*k];
            #pragma unroll
            for (int m=32;m>=1;m>>=1) acc += __shfl_xor(acc, m);
            if (l == 0) angS[w] = tanhf(acc + br[w]) * 3.14159265358979323846f;
        }
    }
    __syncthreads();
    if (T < 36){
        int L = T/6, w = T%6;
        float th = wgt[(L*16+w)*2+0], ph = wgt[(L*16+w)*2+1];
        float s_, c_, sp_, cp_;
        sincosf(0.5f*th, &s_, &c_); sincosf(ph, &sp_, &cp_);
        gates[T][0]=c_; gates[T][1]=s_; gates[T][2]=cp_; gates[T][3]=sp_;
    } else if (T < 42){
        int w = T - 36;
        float sb, cb; sincosf(0.5f*angS[w], &sb, &cb);
        enc[w][0] = cb; enc[w][1] = sb;
    }
    __syncthreads();
    if (T >= 64) return;
    const int l = T;

    float re, im = 0.f;
    {
        float p = 1.f;
        #pragma unroll
        for (int w=0; w<6; ++w) p *= ((l >> (5-w)) & 1) ? enc[w][1] : enc[w][0];
        re = p;
    }
    for (int L=0; L<6; ++L){
        #pragma unroll
        for (int w=0; w<6; ++w){
            const int msk = 1 << (5-w);
            const float c_ = gates[L*6+w][0], s_ = gates[L*6+w][1];
            const float cp_ = gates[L*6+w][2], sp_ = gates[L*6+w][3];
            float pr = __shfl_xor(re, msk), pi = __shfl_xor(im, msk);
            float nr, ni;
            if (l & msk){
                nr = s_*pr + c_*re;  ni = s_*pi + c_*im;
                float tr = nr*cp_ - ni*sp_;
                ni = nr*sp_ + ni*cp_;  nr = tr;
            } else {
                nr = c_*re - s_*pr;  ni = c_*im - s_*pi;
            }
            re = nr; im = ni;
        }
        #pragma unroll
        for (int k=0; k<5; ++k){
            const int cb = 5-k, tm = 1 << (4-k);
            float pr = __shfl_xor(re, tm), pi = __shfl_xor(im, tm);
            bool ct = (l >> cb) & 1;
            re = ct ? pr : re;  im = ct ? pi : im;
        }
    }
    float p = (((l >> 5) & 1) ? -1.f : 1.f) * (re*re + im*im);
    #pragma unroll
    for (int m=32;m>=1;m>>=1) p += __shfl_xor(p, m);
    if (l == 0) out[b] = 1.f/(1.f + expf(-p));
}

extern "C" void kernel_launch(void* const* d_in, const int* in_sizes, int n_in,
                              void* d_out, int out_size, void* d_ws, size_t ws_size,
                              hipStream_t stream){
    (void)in_sizes; (void)n_in; (void)out_size; (void)ws_size;
    const float* x  = (const float*)d_in[0];
    const float* Wc = (const float*)d_in[1];
    const float* bc = (const float*)d_in[2];
    const float* Wr = (const float*)d_in[3];
    const float* br = (const float*)d_in[4];
    const float* wq = (const float*)d_in[5];
    float* fp   = (float*)d_ws;                  // [64][28][512]
    float* outF = (float*)d_out;

    const int dynC = 112*72*2;           // 16128 B
    (void)hipFuncSetAttribute(reinterpret_cast<const void*>(&k_conv_mfma),
                        hipFuncAttributeMaxDynamicSharedMemorySize, dynC);

    k_conv_mfma<<<64*28,512,dynC,stream>>>(x, Wc, bc, fp);
    k_vqc6<<<64,512,0,stream>>>(wq, fp, Wr, br, outF);
}

// Round 24
// 36.461 us; speedup vs baseline: 1.2967x; 1.2967x over previous
//
#include <hip/hip_runtime.h>
#include <hip/hip_bf16.h>
#include <math.h>

// ws layout (floats): [0,917504) fp[64][28][512] conv partials.

typedef _Float16 h4 __attribute__((ext_vector_type(4)));
typedef _Float16 h8 __attribute__((ext_vector_type(8)));
typedef float f32x4 __attribute__((ext_vector_type(4)));

__device__ __forceinline__ h8 cvt8(float4 a, float4 b){
    h8 r; r[0]=(_Float16)a.x; r[1]=(_Float16)a.y; r[2]=(_Float16)a.z; r[3]=(_Float16)a.w;
    r[4]=(_Float16)b.x; r[5]=(_Float16)b.y; r[6]=(_Float16)b.z; r[7]=(_Float16)b.w; return r;
}

// ---------------- conv + relu + partial global-avg-pool via MFMA ----------------
// Grid 64*28, 512 thr, 112 positions (2 output rows). LDS 16KB.
// R19 configuration — proven best across five restructure attempts (R20-R23):
// unconditional Af2 read (pad region keeps it branch-free), 4 N-tiles/wave.
__global__ __launch_bounds__(512) void k_conv_mfma(const float* __restrict__ x,
            const float* __restrict__ Wc, const float* __restrict__ bc,
            float* __restrict__ fp){
    extern __shared__ _Float16 Al[];   // [112][72]
    const int tid = threadIdx.x;
    const int b = blockIdx.x / 28, seg = blockIdx.x % 28;
    for (int idx = tid; idx < 1344; idx += 512){
        int cr = idx / 112, p = idx - cr*112;
        int cc = cr >> 2, r = cr & 3;
        int ro = p / 56, ow = p - ro*56;
        int ih = (seg*2 + ro)*4 + r;
        float4 v = *(const float4*)&x[(((size_t)b*3 + cc)*224 + ih)*224 + ow*4];
        h4 hv; hv[0]=(_Float16)v.x; hv[1]=(_Float16)v.y; hv[2]=(_Float16)v.z; hv[3]=(_Float16)v.w;
        *(h4*)&Al[p*72 + cr*4] = hv;
    }
    for (int idx = tid; idx < 448; idx += 512){
        int p = idx >> 2, j = idx & 3;
        *(h4*)&Al[p*72 + 48 + j*4] = (h4){0,0,0,0};
    }
    const int wv = tid >> 6, lane = tid & 63;
    const int col = lane & 15, kg = lane >> 4;
    const int n0 = wv * 64;
    const h8 hz = {0,0,0,0,0,0,0,0};
    h8 Bf[4], Bf2[4];
    float bias[4], pool[4];
    #pragma unroll
    for (int nt=0; nt<4; ++nt){
        int ch = n0 + nt*16 + col;
        const float* wr = &Wc[ch*48];
        float4 wa = *(const float4*)&wr[kg*8];
        float4 wb = *(const float4*)&wr[kg*8 + 4];
        Bf[nt] = cvt8(wa, wb);
        if (kg < 2){
            float4 wc4 = *(const float4*)&wr[32 + kg*8];
            float4 wd  = *(const float4*)&wr[36 + kg*8];
            Bf2[nt] = cvt8(wc4, wd);
        } else Bf2[nt] = hz;
        bias[nt] = bc[ch];
        pool[nt] = 0.f;
    }
    __syncthreads();
    #pragma unroll
    for (int mt=0; mt<7; ++mt){
        const _Float16* ar = &Al[(mt*16 + col)*72];
        h8 Af  = *(const h8*)&ar[kg*8];
        h8 Af2 = *(const h8*)&ar[32 + kg*8];
        #pragma unroll
        for (int nt=0; nt<4; ++nt){
            f32x4 acc = {0.f,0.f,0.f,0.f};
            acc = __builtin_amdgcn_mfma_f32_16x16x32_f16(Af,  Bf[nt],  acc, 0,0,0);
            acc = __builtin_amdgcn_mfma_f32_16x16x32_f16(Af2, Bf2[nt], acc, 0,0,0);
            #pragma unroll
            for (int j=0;j<4;++j) pool[nt] += fmaxf(acc[j] + bias[nt], 0.f);
        }
    }
    #pragma unroll
    for (int nt=0; nt<4; ++nt){
        pool[nt] += __shfl_xor(pool[nt], 16);
        pool[nt] += __shfl_xor(pool[nt], 32);
    }
    if (lane < 16){
        float* dst = &fp[((b*28 + seg)<<9) + n0 + lane];
        #pragma unroll
        for (int nt=0; nt<4; ++nt) dst[nt*16] = pool[nt];
    }
}

// ---------------- light-cone VQC: 6-qubit statevector ----------------
// M = U^dag Z0 U supported on wires 0..5 (ascending CNOT chain: backward light
// cone grows 1 wire/layer). 512 thr: feat stage (8-wave TLP) -> 6-wave reduce ->
// wave 0 runs the 64-amp circuit via shfl_xor.
__global__ __launch_bounds__(512) void k_vqc6(
        const float* __restrict__ wgt,   // [6][16][2]
        const float* __restrict__ fp,    // [64][28][512]
        const float* __restrict__ Wr, const float* __restrict__ br,
        float* __restrict__ out){
    __shared__ float featL[512];
    __shared__ float gates[36][4];
    __shared__ float enc[6][2];
    __shared__ float angS[6];
    const int T = threadIdx.x;
    const int b = blockIdx.x;

    {
        float s = 0.f;
        #pragma unroll 4
        for (int seg=0; seg<28; ++seg) s += fp[((b*28 + seg)<<9) + T];
        featL[T] = s;
    }
    __syncthreads();
    {
        int w = T >> 6, l = T & 63;
        if (w < 6){
            float acc = 0.f;
            #pragma unroll
            for (int k=0;k<8;++k)
                acc += (featL[l + 64*k] * (1.0f/3136.0f)) * Wr[w*512 + l + 64*k];
            #pragma unroll
            for (int m=32;m>=1;m>>=1) acc += __shfl_xor(acc, m);
            if (l == 0) angS[w] = tanhf(acc + br[w]) * 3.14159265358979323846f;
        }
    }
    __syncthreads();
    if (T < 36){
        int L = T/6, w = T%6;
        float th = wgt[(L*16+w)*2+0], ph = wgt[(L*16+w)*2+1];
        float s_, c_, sp_, cp_;
        sincosf(0.5f*th, &s_, &c_); sincosf(ph, &sp_, &cp_);
        gates[T][0]=c_; gates[T][1]=s_; gates[T][2]=cp_; gates[T][3]=sp_;
    } else if (T < 42){
        int w = T - 36;
        float sb, cb; sincosf(0.5f*angS[w], &sb, &cb);
        enc[w][0] = cb; enc[w][1] = sb;
    }
    __syncthreads();
    if (T >= 64) return;
    const int l = T;

    float re, im = 0.f;
    {
        float p = 1.f;
        #pragma unroll
        for (int w=0; w<6; ++w) p *= ((l >> (5-w)) & 1) ? enc[w][1] : enc[w][0];
        re = p;
    }
    for (int L=0; L<6; ++L){
        #pragma unroll
        for (int w=0; w<6; ++w){
            const int msk = 1 << (5-w);
            const float c_ = gates[L*6+w][0], s_ = gates[L*6+w][1];
            const float cp_ = gates[L*6+w][2], sp_ = gates[L*6+w][3];
            float pr = __shfl_xor(re, msk), pi = __shfl_xor(im, msk);
            float nr, ni;
            if (l & msk){
                nr = s_*pr + c_*re;  ni = s_*pi + c_*im;
                float tr = nr*cp_ - ni*sp_;
                ni = nr*sp_ + ni*cp_;  nr = tr;
            } else {
                nr = c_*re - s_*pr;  ni = c_*im - s_*pi;
            }
            re = nr; im = ni;
        }
        #pragma unroll
        for (int k=0; k<5; ++k){
            const int cb = 5-k, tm = 1 << (4-k);
            float pr = __shfl_xor(re, tm), pi = __shfl_xor(im, tm);
            bool ct = (l >> cb) & 1;
            re = ct ? pr : re;  im = ct ? pi : im;
        }
    }
    float p = (((l >> 5) & 1) ? -1.f : 1.f) * (re*re + im*im);
    #pragma unroll
    for (int m=32;m>=1;m>>=1) p += __shfl_xor(p, m);
    if (l == 0) out[b] = 1.f/(1.f + expf(-p));
}

extern "C" void kernel_launch(void* const* d_in, const int* in_sizes, int n_in,
                              void* d_out, int out_size, void* d_ws, size_t ws_size,
                              hipStream_t stream){
    (void)in_sizes; (void)n_in; (void)out_size; (void)ws_size;
    const float* x  = (const float*)d_in[0];
    const float* Wc = (const float*)d_in[1];
    const float* bc = (const float*)d_in[2];
    const float* Wr = (const float*)d_in[3];
    const float* br = (const float*)d_in[4];
    const float* wq = (const float*)d_in[5];
    float* fp   = (float*)d_ws;                  // [64][28][512]
    float* outF = (float*)d_out;

    const int dynC = 112*72*2;           // 16128 B
    (void)hipFuncSetAttribute(reinterpret_cast<const void*>(&k_conv_mfma),
                        hipFuncAttributeMaxDynamicSharedMemorySize, dynC);

    k_conv_mfma<<<64*28,512,dynC,stream>>>(x, Wc, bc, fp);
    k_vqc6<<<64,512,0,stream>>>(wq, fp, Wr, br, outF);
}